// Round 1
// baseline (71.544 us; speedup 1.0000x reference)
//
#include <hip/hip_runtime.h>
#include <math.h>

#define HW    65536
#define OC    128      // quantum channels
#define C2    256      // 2*OUT_C bn channels
#define NANS  2
#define EPS_  1e-5f

struct cplx { float re, im; };
__device__ __forceinline__ cplx cmul(cplx a, cplx b){ return {a.re*b.re - a.im*b.im, a.re*b.im + a.im*b.re}; }
__device__ __forceinline__ cplx cadd(cplx a, cplx b){ return {a.re+b.re, a.im+b.im}; }

// ---------------- Kernel A: partial stats over c0, c1 (sample 0) ----------------
__global__ __launch_bounds__(256) void qf_stats_partial(const float* __restrict__ coords,
                                                        float* __restrict__ part) {
    int i = blockIdx.x * 256 + threadIdx.x;
    float c0 = coords[i];
    float c1 = coords[HW + i];
    float v[5] = {c0, c1, c0*c0, c1*c1, c0*c1};
    #pragma unroll
    for (int k = 0; k < 5; k++) {
        float x = v[k];
        #pragma unroll
        for (int off = 32; off; off >>= 1) x += __shfl_down(x, off, 64);
        v[k] = x;
    }
    __shared__ float sm[4][5];
    int lane = threadIdx.x & 63, wid = threadIdx.x >> 6;
    if (lane == 0) {
        #pragma unroll
        for (int k = 0; k < 5; k++) sm[wid][k] = v[k];
    }
    __syncthreads();
    if (threadIdx.x == 0) {
        #pragma unroll
        for (int k = 0; k < 5; k++)
            part[blockIdx.x * 5 + k] = sm[0][k] + sm[1][k] + sm[2][k] + sm[3][k];
    }
}

// ---------------- circuit helpers (precompute only) ----------------
__device__ __forceinline__ void make_u3(const float* __restrict__ p, cplx U[2][2]) {
    float th = p[0], ph = p[1], lm = p[2];
    float ct = cosf(th * 0.5f), st = sinf(th * 0.5f);
    float cl = cosf(lm), sl = sinf(lm);
    float cp = cosf(ph), sp = sinf(ph);
    float cpl = cosf(ph + lm), spl = sinf(ph + lm);
    U[0][0] = {ct, 0.f};
    U[0][1] = {-cl * st, -sl * st};
    U[1][0] = {cp * st, sp * st};
    U[1][1] = {cpl * ct, spl * ct};
}
__device__ __forceinline__ void apply_u3_w0(cplx v[4], const cplx U[2][2]) {
    cplx a0 = cadd(cmul(U[0][0], v[0]), cmul(U[0][1], v[2]));
    cplx a1 = cadd(cmul(U[0][0], v[1]), cmul(U[0][1], v[3]));
    cplx a2 = cadd(cmul(U[1][0], v[0]), cmul(U[1][1], v[2]));
    cplx a3 = cadd(cmul(U[1][0], v[1]), cmul(U[1][1], v[3]));
    v[0]=a0; v[1]=a1; v[2]=a2; v[3]=a3;
}
__device__ __forceinline__ void apply_u3_w1(cplx v[4], const cplx U[2][2]) {
    cplx a0 = cadd(cmul(U[0][0], v[0]), cmul(U[0][1], v[1]));
    cplx a1 = cadd(cmul(U[1][0], v[0]), cmul(U[1][1], v[1]));
    cplx a2 = cadd(cmul(U[0][0], v[2]), cmul(U[0][1], v[3]));
    cplx a3 = cadd(cmul(U[1][0], v[2]), cmul(U[1][1], v[3]));
    v[0]=a0; v[1]=a1; v[2]=a2; v[3]=a3;
}
__device__ __forceinline__ void apply_level(cplx v[4], const float* __restrict__ qp, int lvl, int o) {
    #pragma unroll
    for (int j = 0; j < NANS; j++) {
        cplx U0[2][2], U1[2][2];
        make_u3(qp + (((lvl * NANS + j) * C2) + 2 * o    ) * 3, U0);
        make_u3(qp + (((lvl * NANS + j) * C2) + 2 * o + 1) * 3, U1);
        apply_u3_w0(v, U0);
        apply_u3_w1(v, U1);
        cplx t = v[2]; v[2] = v[3]; v[3] = t;   // CNOT: swap |10> <-> |11>
    }
}

// ---------------- Kernel B: finalize stats -> BN coeffs + circuit constants ----------------
__global__ __launch_bounds__(256) void qf_finalize(const float* __restrict__ part,
                                                   const float* __restrict__ F,
                                                   const float* __restrict__ qparam,
                                                   const float* __restrict__ g,
                                                   const float* __restrict__ bb,
                                                   float* __restrict__ ws_bn,
                                                   float* __restrict__ ws_mat) {
    int t = threadIdx.x;
    __shared__ float stats[5];
    {
        float s[5] = {0,0,0,0,0};
        if (t < 64) {
            for (int b = t; b < 256; b += 64)
                #pragma unroll
                for (int k = 0; k < 5; k++) s[k] += part[b * 5 + k];
            #pragma unroll
            for (int k = 0; k < 5; k++) {
                float x = s[k];
                #pragma unroll
                for (int off = 32; off; off >>= 1) x += __shfl_down(x, off, 64);
                s[k] = x;
            }
        }
        if (t == 0) {
            #pragma unroll
            for (int k = 0; k < 5; k++) stats[k] = s[k];
        }
    }
    __syncthreads();

    // BN affine per bn-channel:  x[ch,p] = A*c0[p] + B*c1[p] + C
    {
        const float Ninv = 1.0f / 65536.0f;
        float m0 = stats[0] * Ninv, m1 = stats[1] * Ninv;
        float F0 = F[t * 2 + 0], F1 = F[t * 2 + 1];
        float mean = F0 * m0 + F1 * m1;
        float ex2  = (F0 * F0 * stats[2] + 2.f * F0 * F1 * stats[4] + F1 * F1 * stats[3]) * Ninv;
        float var  = ex2 - mean * mean;
        float scale = g[t] / sqrtf(var + EPS_);
        ws_bn[t * 3 + 0] = F0 * scale;
        ws_bn[t * 3 + 1] = F1 * scale;
        ws_bn[t * 3 + 2] = bb[t] - mean * scale;
    }

    // circuit constants per quantum channel
    if (t < OC) {
        int o = t;
        cplx psi0[4] = {{1,0},{0,0},{0,0},{0,0}};
        apply_level(psi0, qparam, 0, o);
        float* mat = ws_mat + o * 64;
        // B1 = A1 with psi0 folded into columns
        #pragma unroll
        for (int k = 0; k < 4; k++) {
            cplx v[4] = {{0,0},{0,0},{0,0},{0,0}};
            v[k] = {1.f, 0.f};
            apply_level(v, qparam, 1, o);
            #pragma unroll
            for (int r = 0; r < 4; r++) {
                cplx bm = cmul(v[r], psi0[k]);
                mat[(r * 4 + k) * 2 + 0] = bm.re;
                mat[(r * 4 + k) * 2 + 1] = bm.im;
            }
        }
        // A2
        #pragma unroll
        for (int k = 0; k < 4; k++) {
            cplx v[4] = {{0,0},{0,0},{0,0},{0,0}};
            v[k] = {1.f, 0.f};
            apply_level(v, qparam, 2, o);
            #pragma unroll
            for (int r = 0; r < 4; r++) {
                mat[32 + (r * 4 + k) * 2 + 0] = v[r].re;
                mat[32 + (r * 4 + k) * 2 + 1] = v[r].im;
            }
        }
    }
}

// ---------------- Kernel C: main per-pixel evaluation ----------------
__global__ __launch_bounds__(256) void qf_main(const float* __restrict__ coords,
                                               const float* __restrict__ ws_bn,
                                               const float* __restrict__ ws_mat,
                                               float* __restrict__ out) {
    int p = blockIdx.x * 256 + threadIdx.x;
    int o = blockIdx.y;                          // uniform per block
    float c0 = coords[p];
    float c1 = coords[HW + p];
    const float* __restrict__ bn = ws_bn + 6 * o;
    float x0 = bn[0] * c0 + bn[1] * c1 + bn[2];
    float x1 = bn[3] * c0 + bn[4] * c1 + bn[5];
    float a  = 0.5f * (x0 + x1);
    float b  = 0.5f * (x0 - x1);
    float sa, ca, sb, cb;
    __sincosf(a, &sa, &ca);
    __sincosf(b, &sb, &cb);
    // d = [conj(p), conj(q), q, p], p = e^{i a}, q = e^{i b}
    cplx d[4] = {{ca, -sa}, {cb, -sb}, {cb, sb}, {ca, sa}};

    const float* __restrict__ mat = ws_mat + o * 64;
    cplx v3[4];
    #pragma unroll
    for (int r = 0; r < 4; r++) {
        cplx acc = {0.f, 0.f};
        #pragma unroll
        for (int k = 0; k < 4; k++) {
            cplx m = {mat[(r * 4 + k) * 2], mat[(r * 4 + k) * 2 + 1]};
            acc = cadd(acc, cmul(m, d[k]));
        }
        v3[r] = cmul(d[r], acc);     // second RZ layer (same x)
    }
    float ev = 0.f;
    #pragma unroll
    for (int r = 0; r < 4; r++) {
        cplx acc = {0.f, 0.f};
        #pragma unroll
        for (int k = 0; k < 4; k++) {
            cplx m = {mat[32 + (r * 4 + k) * 2], mat[32 + (r * 4 + k) * 2 + 1]};
            acc = cadd(acc, cmul(m, v3[k]));
        }
        float pr = acc.re * acc.re + acc.im * acc.im;
        ev += (r < 2) ? pr : -pr;
    }
    size_t base = (size_t)o * HW + (size_t)p;
    const size_t plane = (size_t)OC * HW;
    out[base] = ev;
    out[base + plane] = ev;
    out[base + 2 * plane] = ev;
    out[base + 3 * plane] = ev;
}

extern "C" void kernel_launch(void* const* d_in, const int* in_sizes, int n_in,
                              void* d_out, int out_size, void* d_ws, size_t ws_size,
                              hipStream_t stream) {
    const float* coords = (const float*)d_in[0];
    const float* F      = (const float*)d_in[1];
    const float* qparam = (const float*)d_in[2];
    const float* g      = (const float*)d_in[3];
    const float* bb     = (const float*)d_in[4];
    float* out = (float*)d_out;

    float* ws   = (float*)d_ws;
    float* part = ws;              // 256*5 = 1280 floats
    float* wsbn = ws + 1280;       // 256*3 = 768 floats
    float* wsmat= ws + 2048;       // 128*64 = 8192 floats

    qf_stats_partial<<<dim3(256), dim3(256), 0, stream>>>(coords, part);
    qf_finalize<<<dim3(1), dim3(256), 0, stream>>>(part, F, qparam, g, bb, wsbn, wsmat);
    qf_main<<<dim3(256, 128), dim3(256), 0, stream>>>(coords, wsbn, wsmat, out);
}